// Round 1
// baseline (227.163 us; speedup 1.0000x reference)
//
#include <hip/hip_runtime.h>
#include <hip/hip_bf16.h>
#include <stdint.h>

#define KAUG 160   // 128 LoRA cols + 8 gate cols + 24 zero pad
#define M_ROWS 16384

typedef __attribute__((ext_vector_type(8))) __bf16 bf16x8;
typedef __attribute__((ext_vector_type(4))) float f32x4;

__device__ __forceinline__ unsigned short f2b(float f) {
  unsigned int u = __builtin_bit_cast(unsigned int, f);
  u = (u + 0x7fffu + ((u >> 16) & 1u)) >> 16;
  return (unsigned short)u;
}

__device__ __forceinline__ void lds_load16(const unsigned short* g, unsigned short* l) {
  __builtin_amdgcn_global_load_lds(
      (const __attribute__((address_space(1))) void*)g,
      (__attribute__((address_space(3))) void*)l, 16, 0, 0);
}

// ---------------- prep kernels ----------------

__global__ void gate_kernel(const int* __restrict__ dom, const float* __restrict__ emb,
                            const float* __restrict__ gW, const float* __restrict__ gb,
                            float* __restrict__ gate) {
  int i = blockIdx.x * blockDim.x + threadIdx.x;
  int d = dom[i];
  float e0 = emb[d*4+0], e1 = emb[d*4+1], e2 = emb[d*4+2], e3 = emb[d*4+3];
  float l[8]; float mx = -1e30f;
#pragma unroll
  for (int j = 0; j < 8; j++) {
    l[j] = e0*gW[j] + e1*gW[8+j] + e2*gW[16+j] + e3*gW[24+j] + gb[j];
    mx = fmaxf(mx, l[j]);
  }
  float s = 0.f;
#pragma unroll
  for (int j = 0; j < 8; j++) { l[j] = __expf(l[j] - mx); s += l[j]; }
  float inv = 1.0f / s;
#pragma unroll
  for (int j = 0; j < 8; j++) gate[i*8+j] = l[j] * inv;
}

__global__ void f32_to_bf16_vec(const float* __restrict__ in, unsigned short* __restrict__ out, int n4) {
  int i = blockIdx.x * blockDim.x + threadIdx.x;
  if (i >= n4) return;
  float4 v = ((const float4*)in)[i];
  ushort4 o;
  o.x = f2b(v.x); o.y = f2b(v.y); o.z = f2b(v.z); o.w = f2b(v.w);
  ((ushort4*)out)[i] = o;
}

// Wt[n*K + k] = bf16(W[k*N + n])  : weight transpose [K,N]->[N,K]
__global__ void build_wt(const float* __restrict__ W, unsigned short* __restrict__ Wt,
                         int K, int N, long total) {
  long i = (long)blockIdx.x * blockDim.x + threadIdx.x;
  if (i >= total) return;
  int k = (int)(i % K); int n = (int)(i / K);
  Wt[i] = f2b(W[(long)k * N + n]);
}

// Aft[c*P + p] = bf16(A[e][p][r]), c = e*16+r  (A is [E,P,16])
__global__ void build_aft(const float* __restrict__ A, unsigned short* __restrict__ Aft,
                          int P, long total) {
  long i = (long)blockIdx.x * blockDim.x + threadIdx.x;
  if (i >= total) return;
  int pp = (int)(i % P); int c = (int)(i / P);
  int e = c >> 4, r = c & 15;
  Aft[i] = f2b(A[((long)e * P + pp) * 16 + r]);
}

// Bft[n*KAUG + kk]: kk<128 -> B_flat[kk*H+n]; kk in [128,136) -> lb[kk-128][n]; else 0
__global__ void build_bft(const float* __restrict__ Bm, const float* __restrict__ lb,
                          unsigned short* __restrict__ Bft, int H, long total) {
  long i = (long)blockIdx.x * blockDim.x + threadIdx.x;
  if (i >= total) return;
  int kk = (int)(i % KAUG); int n = (int)(i / KAUG);
  float v = 0.f;
  if (kk < 128) v = Bm[(long)kk * H + n];
  else if (kk < 136) v = lb[(long)(kk - 128) * H + n];
  Bft[i] = f2b(v);
}

// tg[b][128+j]: j<8 -> gate[b][j]; j in [8,32) -> 0
__global__ void aug_fill(const float* __restrict__ gate, unsigned short* __restrict__ tg) {
  int i = blockIdx.x * blockDim.x + threadIdx.x;  // M*32 threads
  int j = i & 31; int b = i >> 5;
  float v = (j < 8) ? gate[b*8 + j] : 0.f;
  tg[(long)b * KAUG + 128 + j] = f2b(v);
}

// ---------------- MFMA GEMM (m97-style 128x128 tile, BK=32) ----------------
// C[row,col] = sum_k A[row,k] * Bt[col,k], K-range split across (A1,Bt1,K1) then (A2,Bt2,K2).
// MODE 0: out = bf16(C * gate[row][col>>4]), ldout elems (tg output)
// MODE 1: out = bf16(relu(C + bias[col]))
// MODE 2: out = f32 (relu(C + bias[col]))
template<int MODE>
__global__ __launch_bounds__(256)
void gemm_bt(const unsigned short* __restrict__ A1, int lda1, int K1,
             const unsigned short* __restrict__ A2, int lda2, int K2,
             const unsigned short* __restrict__ Bt1,
             const unsigned short* __restrict__ Bt2,
             const float* __restrict__ bias,
             const float* __restrict__ gate,
             void* __restrict__ outp, int ldout) {
  __shared__ __attribute__((aligned(16))) unsigned short As[128 * 32];
  __shared__ __attribute__((aligned(16))) unsigned short Bs[128 * 32];
  const int t = threadIdx.x;
  const int lane = t & 63, wave = t >> 6;
  const int wr = wave >> 1, wc = wave & 1;
  const int row0 = blockIdx.x * 128, col0 = blockIdx.y * 128;
  const int rl = lane & 15, kg = lane >> 4;

  f32x4 acc[4][4];
#pragma unroll
  for (int m = 0; m < 4; m++)
#pragma unroll
    for (int n = 0; n < 4; n++) acc[m][n] = (f32x4){0.f, 0.f, 0.f, 0.f};

  // staging chunk ids: c = t (+256); chunk c -> row c>>2, k-offset (c&3)*8
  const int ar0 = t >> 2,         ak0 = (t & 3) * 8;
  const int ar1 = (t + 256) >> 2, ak1 = (t & 3) * 8;  // (t+256)&3 == t&3
  unsigned short* asd0 = &As[wave * 512];
  unsigned short* asd1 = &As[wave * 512 + 2048];
  unsigned short* bsd0 = &Bs[wave * 512];
  unsigned short* bsd1 = &Bs[wave * 512 + 2048];

  const int Ktot = K1 + K2;
  for (int kt = 0; kt < Ktot; kt += 32) {
    const unsigned short* asrc; const unsigned short* bsrc;
    long lda, ldb; int kl;
    if (kt < K1) { asrc = A1; bsrc = Bt1; lda = lda1; ldb = K1;   kl = kt; }
    else         { asrc = A2; bsrc = Bt2; lda = lda2; ldb = lda2; kl = kt - K1; }
    lds_load16(asrc + (long)(row0 + ar0) * lda + kl + ak0, asd0);
    lds_load16(asrc + (long)(row0 + ar1) * lda + kl + ak1, asd1);
    lds_load16(bsrc + (long)(col0 + ar0) * ldb + kl + ak0, bsd0);
    lds_load16(bsrc + (long)(col0 + ar1) * ldb + kl + ak1, bsd1);
    __syncthreads();
    bf16x8 af[4], bfv[4];
#pragma unroll
    for (int m = 0; m < 4; m++)
      af[m] = *(const bf16x8*)&As[(wr * 64 + m * 16 + rl) * 32 + kg * 8];
#pragma unroll
    for (int n = 0; n < 4; n++)
      bfv[n] = *(const bf16x8*)&Bs[(wc * 64 + n * 16 + rl) * 32 + kg * 8];
#pragma unroll
    for (int m = 0; m < 4; m++)
#pragma unroll
      for (int n = 0; n < 4; n++)
        acc[m][n] = __builtin_amdgcn_mfma_f32_16x16x32_bf16(af[m], bfv[n], acc[m][n], 0, 0, 0);
    __syncthreads();
  }

#pragma unroll
  for (int m = 0; m < 4; m++) {
#pragma unroll
    for (int n = 0; n < 4; n++) {
#pragma unroll
      for (int j = 0; j < 4; j++) {
        int row = row0 + wr * 64 + m * 16 + kg * 4 + j;
        int col = col0 + wc * 64 + n * 16 + rl;
        float v = acc[m][n][j];
        if (MODE == 0) {
          v *= gate[row * 8 + (col >> 4)];
          ((unsigned short*)outp)[(long)row * ldout + col] = f2b(v);
        } else {
          v += bias[col];
          v = fmaxf(v, 0.f);
          if (MODE == 1) ((unsigned short*)outp)[(long)row * ldout + col] = f2b(v);
          else           ((float*)outp)[(long)row * ldout + col] = v;
        }
      }
    }
  }
}

// ---------------- launch ----------------

extern "C" void kernel_launch(void* const* d_in, const int* in_sizes, int n_in,
                              void* d_out, int out_size, void* d_ws, size_t ws_size,
                              hipStream_t stream) {
  (void)in_sizes; (void)n_in; (void)out_size; (void)ws_size;
  const float* dnn = (const float*)d_in[0];
  const int*   dom = (const int*)d_in[1];
  const float* emb = (const float*)d_in[2];
  const float* gW  = (const float*)d_in[3];
  const float* gb  = (const float*)d_in[4];
  const float* Wm[3]  = {(const float*)d_in[5],  (const float*)d_in[10], (const float*)d_in[15]};
  const float* bm[3]  = {(const float*)d_in[6],  (const float*)d_in[11], (const float*)d_in[16]};
  const float* Am[3]  = {(const float*)d_in[7],  (const float*)d_in[12], (const float*)d_in[17]};
  const float* Bm[3]  = {(const float*)d_in[8],  (const float*)d_in[13], (const float*)d_in[18]};
  const float* lbm[3] = {(const float*)d_in[9],  (const float*)d_in[14], (const float*)d_in[19]};

  const int M = M_ROWS;
  const int dIn[3]  = {1024, 1024, 512};
  const int dOutN[3] = {1024, 512, 256};

  char* p = (char*)d_ws;
  auto carve = [&](size_t bytes) { char* r = p; p += (bytes + 255) & ~(size_t)255; return r; };
  float* gate = (float*)carve((size_t)M * 8 * sizeof(float));
  unsigned short* xb0 = (unsigned short*)carve((size_t)M * 1024 * 2);
  unsigned short* xb1 = (unsigned short*)carve((size_t)M * 1024 * 2);
  unsigned short* tg  = (unsigned short*)carve((size_t)M * KAUG * 2);
  unsigned short *Wt[3], *Aft[3], *Bft[3];
  for (int l = 0; l < 3; l++) {
    Wt[l]  = (unsigned short*)carve((size_t)dOutN[l] * dIn[l] * 2);
    Aft[l] = (unsigned short*)carve((size_t)128 * dIn[l] * 2);
    Bft[l] = (unsigned short*)carve((size_t)dOutN[l] * KAUG * 2);
  }

  gate_kernel<<<M / 256, 256, 0, stream>>>(dom, emb, gW, gb, gate);
  {
    int n4 = M * 1024 / 4;
    f32_to_bf16_vec<<<(n4 + 255) / 256, 256, 0, stream>>>(dnn, xb0, n4);
  }
  for (int l = 0; l < 3; l++) {
    long totW = (long)dOutN[l] * dIn[l];
    build_wt<<<(int)((totW + 255) / 256), 256, 0, stream>>>(Wm[l], Wt[l], dIn[l], dOutN[l], totW);
    long totA = (long)128 * dIn[l];
    build_aft<<<(int)((totA + 255) / 256), 256, 0, stream>>>(Am[l], Aft[l], dIn[l], totA);
    long totB = (long)dOutN[l] * KAUG;
    build_bft<<<(int)((totB + 255) / 256), 256, 0, stream>>>(Bm[l], lbm[l], Bft[l], dOutN[l], totB);
  }
  aug_fill<<<(M * 32) / 256, 256, 0, stream>>>(gate, tg);

  const unsigned short* xin = xb0;
  for (int l = 0; l < 3; l++) {
    int K1 = dIn[l], N = dOutN[l];
    // tg[:, :128] = gate-scaled x @ A_flat
    gemm_bt<0><<<dim3(M / 128, 1), 256, 0, stream>>>(
        xin, K1, K1, nullptr, 0, 0, Aft[l], nullptr, nullptr, gate, (void*)tg, KAUG);
    // out = relu(x @ W + tg_aug @ B_aug + bias)
    if (l == 0)
      gemm_bt<1><<<dim3(M / 128, N / 128), 256, 0, stream>>>(
          xin, K1, K1, tg, KAUG, KAUG, Wt[l], Bft[l], bm[l], nullptr, (void*)xb1, N);
    else if (l == 1)
      gemm_bt<1><<<dim3(M / 128, N / 128), 256, 0, stream>>>(
          xin, K1, K1, tg, KAUG, KAUG, Wt[l], Bft[l], bm[l], nullptr, (void*)xb0, N);
    else
      gemm_bt<2><<<dim3(M / 128, N / 128), 256, 0, stream>>>(
          xin, K1, K1, tg, KAUG, KAUG, Wt[l], Bft[l], bm[l], nullptr, d_out, N);
    xin = (l == 0) ? xb1 : xb0;
  }
}

// Round 2
// 212.651 us; speedup vs baseline: 1.0682x; 1.0682x over previous
//
#include <hip/hip_runtime.h>
#include <hip/hip_bf16.h>
#include <stdint.h>

#define KAUG 160   // 128 LoRA cols + 8 gate cols + 24 zero pad
#define M_ROWS 16384

typedef __attribute__((ext_vector_type(8))) __bf16 bf16x8;
typedef __attribute__((ext_vector_type(4))) float f32x4;

__device__ __forceinline__ unsigned short f2b(float f) {
  unsigned int u = __builtin_bit_cast(unsigned int, f);
  u = (u + 0x7fffu + ((u >> 16) & 1u)) >> 16;
  return (unsigned short)u;
}

__device__ __forceinline__ void lds_load16(const unsigned short* g, unsigned short* l) {
  __builtin_amdgcn_global_load_lds(
      (const __attribute__((address_space(1))) void*)g,
      (__attribute__((address_space(3))) void*)l, 16, 0, 0);
}

// ---------------- prep kernels ----------------

__global__ void gate_kernel(const int* __restrict__ dom, const float* __restrict__ emb,
                            const float* __restrict__ gW, const float* __restrict__ gb,
                            float* __restrict__ gate) {
  int i = blockIdx.x * blockDim.x + threadIdx.x;
  int d = dom[i];
  float e0 = emb[d*4+0], e1 = emb[d*4+1], e2 = emb[d*4+2], e3 = emb[d*4+3];
  float l[8]; float mx = -1e30f;
#pragma unroll
  for (int j = 0; j < 8; j++) {
    l[j] = e0*gW[j] + e1*gW[8+j] + e2*gW[16+j] + e3*gW[24+j] + gb[j];
    mx = fmaxf(mx, l[j]);
  }
  float s = 0.f;
#pragma unroll
  for (int j = 0; j < 8; j++) { l[j] = __expf(l[j] - mx); s += l[j]; }
  float inv = 1.0f / s;
#pragma unroll
  for (int j = 0; j < 8; j++) gate[i*8+j] = l[j] * inv;
}

__global__ void f32_to_bf16_vec(const float* __restrict__ in, unsigned short* __restrict__ out, int n4) {
  int i = blockIdx.x * blockDim.x + threadIdx.x;
  if (i >= n4) return;
  float4 v = ((const float4*)in)[i];
  ushort4 o;
  o.x = f2b(v.x); o.y = f2b(v.y); o.z = f2b(v.z); o.w = f2b(v.w);
  ((ushort4*)out)[i] = o;
}

// Wt[n*K + k] = bf16(W[k*N + n])  : weight transpose [K,N]->[N,K]
__global__ void build_wt(const float* __restrict__ W, unsigned short* __restrict__ Wt,
                         int K, int N, long total) {
  long i = (long)blockIdx.x * blockDim.x + threadIdx.x;
  if (i >= total) return;
  int k = (int)(i % K); int n = (int)(i / K);
  Wt[i] = f2b(W[(long)k * N + n]);
}

// Aft[c*P + p] = bf16(A[e][p][r]), c = e*16+r  (A is [E,P,16])
__global__ void build_aft(const float* __restrict__ A, unsigned short* __restrict__ Aft,
                          int P, long total) {
  long i = (long)blockIdx.x * blockDim.x + threadIdx.x;
  if (i >= total) return;
  int pp = (int)(i % P); int c = (int)(i / P);
  int e = c >> 4, r = c & 15;
  Aft[i] = f2b(A[((long)e * P + pp) * 16 + r]);
}

// Bft[n*KAUG + kk]: kk<128 -> B_flat[kk*H+n]; kk in [128,136) -> lb[kk-128][n]; else 0
__global__ void build_bft(const float* __restrict__ Bm, const float* __restrict__ lb,
                          unsigned short* __restrict__ Bft, int H, long total) {
  long i = (long)blockIdx.x * blockDim.x + threadIdx.x;
  if (i >= total) return;
  int kk = (int)(i % KAUG); int n = (int)(i / KAUG);
  float v = 0.f;
  if (kk < 128) v = Bm[(long)kk * H + n];
  else if (kk < 136) v = lb[(long)(kk - 128) * H + n];
  Bft[i] = f2b(v);
}

// tg[b][128+j]: j<8 -> gate[b][j]; j in [8,32) -> 0
__global__ void aug_fill(const float* __restrict__ gate, unsigned short* __restrict__ tg) {
  int i = blockIdx.x * blockDim.x + threadIdx.x;  // M*32 threads
  int j = i & 31; int b = i >> 5;
  float v = (j < 8) ? gate[b*8 + j] : 0.f;
  tg[(long)b * KAUG + 128 + j] = f2b(v);
}

// ---------------- MFMA GEMM: prefetch double-buffer + LDS XOR swizzle ----------------
// C[row,col] = sum_k A[row,k] * Bt[col,k], K split (A1,Bt1,K1) then (A2,Bt2,K2).
// MODE 0: out = bf16(C * gate[row][col>>4])   (tg output)
// MODE 1: out = bf16(relu(C + bias[col]))
// MODE 2: out = f32 (relu(C + bias[col]))
// MREP: per-wave M repeat; tile rows BM = MREP*32 (4 -> 128, 2 -> 64).
//
// LDS tile layout: [BM rows][32 k] bf16, split in 16B chunks (4 per row).
// Swizzle: chunk (r, cc) holds global (r, cc ^ ((r>>1)&3)).  Applied as
// inverse-permuted GLOBAL source (global_load_lds dest stays linear, rule #21)
// and the same XOR on the fragment read -> 2-way banks (free) instead of 8-way.
template<int MODE, int MREP>
__global__ __launch_bounds__(256)
void gemm_bt(const unsigned short* __restrict__ A1, int lda1, int K1,
             const unsigned short* __restrict__ A2, int lda2, int K2,
             const unsigned short* __restrict__ Bt1,
             const unsigned short* __restrict__ Bt2,
             const float* __restrict__ bias,
             const float* __restrict__ gate,
             void* __restrict__ outp, int ldout) {
  constexpr int BM = MREP * 32;
  __shared__ __attribute__((aligned(16))) unsigned short As[2][BM * 32];
  __shared__ __attribute__((aligned(16))) unsigned short Bs[2][128 * 32];
  const int t = threadIdx.x;
  const int lane = t & 63, wave = t >> 6;
  const int wr = wave >> 1, wc = wave & 1;
  const int row0 = blockIdx.x * BM, col0 = blockIdx.y * 128;
  const int rl = lane & 15, kg = lane >> 4;
  // read-side swizzled k-chunk (row base is a multiple of 16 -> (row>>1)&3 == (rl>>1)&3)
  const int kswz = kg ^ ((rl >> 1) & 3);

  // staging: thread t covers chunk t (16B) at linear LDS byte t*16;
  // source row sr0 = t>>2, source k-chunk inverse-swizzled:
  const int sr0 = t >> 2;
  const int sc0 = (((t & 3) ^ ((sr0 >> 1) & 3))) * 8;   // elements
  // chunk t+256: row sr0+64, same sc0 ((r+64)>>1 preserves &3)

  f32x4 acc[MREP][4];
#pragma unroll
  for (int m = 0; m < MREP; m++)
#pragma unroll
    for (int n = 0; n < 4; n++) acc[m][n] = (f32x4){0.f, 0.f, 0.f, 0.f};

  auto stage = [&](int buf, int kt) {
    const unsigned short* asrc; const unsigned short* bsrc;
    long lda, ldb; int kl;
    if (kt < K1) { asrc = A1; bsrc = Bt1; lda = lda1; ldb = K1;   kl = kt; }
    else         { asrc = A2; bsrc = Bt2; lda = lda2; ldb = lda2; kl = kt - K1; }
    unsigned short* ab = &As[buf][0];
    unsigned short* bb = &Bs[buf][0];
    lds_load16(asrc + (long)(row0 + sr0) * lda + kl + sc0, ab + t * 8);
    if constexpr (MREP == 4)
      lds_load16(asrc + (long)(row0 + sr0 + 64) * lda + kl + sc0, ab + t * 8 + 2048);
    lds_load16(bsrc + (long)(col0 + sr0) * ldb + kl + sc0, bb + t * 8);
    lds_load16(bsrc + (long)(col0 + sr0 + 64) * ldb + kl + sc0, bb + t * 8 + 2048);
  };

  const int Ktot = K1 + K2;
  stage(0, 0);
  __syncthreads();           // compiler emits vmcnt(0) before barrier
  int cur = 0;
  for (int kt = 0; kt < Ktot; kt += 32) {
    if (kt + 32 < Ktot) stage(cur ^ 1, kt + 32);   // prefetch next tile
    bf16x8 af[MREP], bfv[4];
#pragma unroll
    for (int m = 0; m < MREP; m++)
      af[m] = *(const bf16x8*)&As[cur][(wr * (MREP * 16) + m * 16 + rl) * 32 + kswz * 8];
#pragma unroll
    for (int n = 0; n < 4; n++)
      bfv[n] = *(const bf16x8*)&Bs[cur][(wc * 64 + n * 16 + rl) * 32 + kswz * 8];
    __builtin_amdgcn_s_setprio(1);
#pragma unroll
    for (int m = 0; m < MREP; m++)
#pragma unroll
      for (int n = 0; n < 4; n++)
        acc[m][n] = __builtin_amdgcn_mfma_f32_16x16x32_bf16(af[m], bfv[n], acc[m][n], 0, 0, 0);
    __builtin_amdgcn_s_setprio(0);
    __syncthreads();          // drains prefetch (vmcnt(0)) + ds_reads
    cur ^= 1;
  }

#pragma unroll
  for (int m = 0; m < MREP; m++) {
#pragma unroll
    for (int n = 0; n < 4; n++) {
#pragma unroll
      for (int j = 0; j < 4; j++) {
        int row = row0 + wr * (MREP * 16) + m * 16 + kg * 4 + j;
        int col = col0 + wc * 64 + n * 16 + rl;
        float v = acc[m][n][j];
        if (MODE == 0) {
          v *= gate[row * 8 + (col >> 4)];
          ((unsigned short*)outp)[(long)row * ldout + col] = f2b(v);
        } else {
          v += bias[col];
          v = fmaxf(v, 0.f);
          if (MODE == 1) ((unsigned short*)outp)[(long)row * ldout + col] = f2b(v);
          else           ((float*)outp)[(long)row * ldout + col] = v;
        }
      }
    }
  }
}

// ---------------- launch ----------------

extern "C" void kernel_launch(void* const* d_in, const int* in_sizes, int n_in,
                              void* d_out, int out_size, void* d_ws, size_t ws_size,
                              hipStream_t stream) {
  (void)in_sizes; (void)n_in; (void)out_size; (void)ws_size;
  const float* dnn = (const float*)d_in[0];
  const int*   dom = (const int*)d_in[1];
  const float* emb = (const float*)d_in[2];
  const float* gW  = (const float*)d_in[3];
  const float* gb  = (const float*)d_in[4];
  const float* Wm[3]  = {(const float*)d_in[5],  (const float*)d_in[10], (const float*)d_in[15]};
  const float* bm[3]  = {(const float*)d_in[6],  (const float*)d_in[11], (const float*)d_in[16]};
  const float* Am[3]  = {(const float*)d_in[7],  (const float*)d_in[12], (const float*)d_in[17]};
  const float* Bm[3]  = {(const float*)d_in[8],  (const float*)d_in[13], (const float*)d_in[18]};
  const float* lbm[3] = {(const float*)d_in[9],  (const float*)d_in[14], (const float*)d_in[19]};

  const int M = M_ROWS;
  const int dIn[3]  = {1024, 1024, 512};
  const int dOutN[3] = {1024, 512, 256};

  char* p = (char*)d_ws;
  auto carve = [&](size_t bytes) { char* r = p; p += (bytes + 255) & ~(size_t)255; return r; };
  float* gate = (float*)carve((size_t)M * 8 * sizeof(float));
  unsigned short* xb0 = (unsigned short*)carve((size_t)M * 1024 * 2);
  unsigned short* xb1 = (unsigned short*)carve((size_t)M * 1024 * 2);
  unsigned short* tg  = (unsigned short*)carve((size_t)M * KAUG * 2);
  unsigned short *Wt[3], *Aft[3], *Bft[3];
  for (int l = 0; l < 3; l++) {
    Wt[l]  = (unsigned short*)carve((size_t)dOutN[l] * dIn[l] * 2);
    Aft[l] = (unsigned short*)carve((size_t)128 * dIn[l] * 2);
    Bft[l] = (unsigned short*)carve((size_t)dOutN[l] * KAUG * 2);
  }

  gate_kernel<<<M / 256, 256, 0, stream>>>(dom, emb, gW, gb, gate);
  {
    int n4 = M * 1024 / 4;
    f32_to_bf16_vec<<<(n4 + 255) / 256, 256, 0, stream>>>(dnn, xb0, n4);
  }
  for (int l = 0; l < 3; l++) {
    long totW = (long)dOutN[l] * dIn[l];
    build_wt<<<(int)((totW + 255) / 256), 256, 0, stream>>>(Wm[l], Wt[l], dIn[l], dOutN[l], totW);
    long totA = (long)128 * dIn[l];
    build_aft<<<(int)((totA + 255) / 256), 256, 0, stream>>>(Am[l], Aft[l], dIn[l], totA);
    long totB = (long)dOutN[l] * KAUG;
    build_bft<<<(int)((totB + 255) / 256), 256, 0, stream>>>(Bm[l], lbm[l], Bft[l], dOutN[l], totB);
  }
  aug_fill<<<(M * 32) / 256, 256, 0, stream>>>(gate, tg);

  const unsigned short* xin = xb0;
  for (int l = 0; l < 3; l++) {
    int K1 = dIn[l], N = dOutN[l];
    // tg[:, :128] = gate-scaled x @ A_flat   (64-row tiles -> 256 blocks)
    gemm_bt<0, 2><<<dim3(M / 64, 1), 256, 0, stream>>>(
        xin, K1, K1, nullptr, 0, 0, Aft[l], nullptr, nullptr, gate, (void*)tg, KAUG);
    // out = relu(x @ W + tg_aug @ B_aug + bias)
    if (l == 0)
      gemm_bt<1, 4><<<dim3(M / 128, N / 128), 256, 0, stream>>>(
          xin, K1, K1, tg, KAUG, KAUG, Wt[l], Bft[l], bm[l], nullptr, (void*)xb1, N);
    else if (l == 1)
      gemm_bt<1, 4><<<dim3(M / 128, N / 128), 256, 0, stream>>>(
          xin, K1, K1, tg, KAUG, KAUG, Wt[l], Bft[l], bm[l], nullptr, (void*)xb0, N);
    else
      gemm_bt<2, 4><<<dim3(M / 128, N / 128), 256, 0, stream>>>(
          xin, K1, K1, tg, KAUG, KAUG, Wt[l], Bft[l], bm[l], nullptr, d_out, N);
    xin = (l == 0) ? xb1 : xb0;
  }
}

// Round 3
// 199.667 us; speedup vs baseline: 1.1377x; 1.0650x over previous
//
#include <hip/hip_runtime.h>
#include <hip/hip_bf16.h>
#include <stdint.h>

#define KAUG 192   // 128 LoRA cols + 8 gate cols + 56 zero pad (multiple of 64)
#define M_ROWS 16384

typedef __attribute__((ext_vector_type(8))) __bf16 bf16x8;
typedef __attribute__((ext_vector_type(4))) float f32x4;

__device__ __forceinline__ unsigned short f2b(float f) {
  unsigned int u = __builtin_bit_cast(unsigned int, f);
  u = (u + 0x7fffu + ((u >> 16) & 1u)) >> 16;
  return (unsigned short)u;
}

__device__ __forceinline__ void lds_load16(const unsigned short* g, unsigned short* l) {
  __builtin_amdgcn_global_load_lds(
      (const __attribute__((address_space(1))) void*)g,
      (__attribute__((address_space(3))) void*)l, 16, 0, 0);
}

// ---------------- prep kernels ----------------

__global__ void gate_kernel(const int* __restrict__ dom, const float* __restrict__ emb,
                            const float* __restrict__ gW, const float* __restrict__ gb,
                            float* __restrict__ gate) {
  int i = blockIdx.x * blockDim.x + threadIdx.x;
  int d = dom[i];
  float e0 = emb[d*4+0], e1 = emb[d*4+1], e2 = emb[d*4+2], e3 = emb[d*4+3];
  float l[8]; float mx = -1e30f;
#pragma unroll
  for (int j = 0; j < 8; j++) {
    l[j] = e0*gW[j] + e1*gW[8+j] + e2*gW[16+j] + e3*gW[24+j] + gb[j];
    mx = fmaxf(mx, l[j]);
  }
  float s = 0.f;
#pragma unroll
  for (int j = 0; j < 8; j++) { l[j] = __expf(l[j] - mx); s += l[j]; }
  float inv = 1.0f / s;
#pragma unroll
  for (int j = 0; j < 8; j++) gate[i*8+j] = l[j] * inv;
}

__global__ void f32_to_bf16_vec(const float* __restrict__ in, unsigned short* __restrict__ out, int n4) {
  int i = blockIdx.x * blockDim.x + threadIdx.x;
  if (i >= n4) return;
  float4 v = ((const float4*)in)[i];
  ushort4 o;
  o.x = f2b(v.x); o.y = f2b(v.y); o.z = f2b(v.z); o.w = f2b(v.w);
  ((ushort4*)out)[i] = o;
}

// Wt[n*K + k] = bf16(W[k*N + n])
__global__ void build_wt(const float* __restrict__ W, unsigned short* __restrict__ Wt,
                         int K, int N, long total) {
  long i = (long)blockIdx.x * blockDim.x + threadIdx.x;
  if (i >= total) return;
  int k = (int)(i % K); int n = (int)(i / K);
  Wt[i] = f2b(W[(long)k * N + n]);
}

// Aft[c*P + p] = bf16(A[e][p][r]), c = e*16+r
__global__ void build_aft(const float* __restrict__ A, unsigned short* __restrict__ Aft,
                          int P, long total) {
  long i = (long)blockIdx.x * blockDim.x + threadIdx.x;
  if (i >= total) return;
  int pp = (int)(i % P); int c = (int)(i / P);
  int e = c >> 4, r = c & 15;
  Aft[i] = f2b(A[((long)e * P + pp) * 16 + r]);
}

// Bft[n*KAUG + kk]: kk<128 -> B_flat[kk*H+n]; kk in [128,136) -> lb[kk-128][n]; else 0
__global__ void build_bft(const float* __restrict__ Bm, const float* __restrict__ lb,
                          unsigned short* __restrict__ Bft, int H, long total) {
  long i = (long)blockIdx.x * blockDim.x + threadIdx.x;
  if (i >= total) return;
  int kk = (int)(i % KAUG); int n = (int)(i / KAUG);
  float v = 0.f;
  if (kk < 128) v = Bm[(long)kk * H + n];
  else if (kk < 136) v = lb[(long)(kk - 128) * H + n];
  Bft[i] = f2b(v);
}

// tg[b][128+j]: j<8 -> gate[b][j]; j in [8,64) -> 0
__global__ void aug_fill(const float* __restrict__ gate, unsigned short* __restrict__ tg) {
  int i = blockIdx.x * blockDim.x + threadIdx.x;  // M*64 threads
  int j = i & 63; int b = i >> 6;
  float v = (j < 8) ? gate[b*8 + j] : 0.f;
  tg[(long)b * KAUG + 128 + j] = f2b(v);
}

// ---------------- 2-phase 64-row GEMM (x@A only, MODE 0) ----------------
template<int MODE, int MREP>
__global__ __launch_bounds__(256)
void gemm2ph(const unsigned short* __restrict__ A1, int lda1, int K1,
             const unsigned short* __restrict__ Bt1,
             const float* __restrict__ gate,
             void* __restrict__ outp, int ldout) {
  constexpr int BM = MREP * 32;
  __shared__ __attribute__((aligned(16))) unsigned short As[2][BM * 32];
  __shared__ __attribute__((aligned(16))) unsigned short Bs[2][128 * 32];
  const int t = threadIdx.x;
  const int lane = t & 63, wave = t >> 6;
  const int wr = wave >> 1, wc = wave & 1;
  const int row0 = blockIdx.x * BM, col0 = blockIdx.y * 128;
  const int rl = lane & 15, kg = lane >> 4;
  const int kswz = kg ^ ((rl >> 1) & 3);
  const int sr0 = t >> 2;
  const int sc0 = (((t & 3) ^ ((sr0 >> 1) & 3))) * 8;

  f32x4 acc[MREP][4];
#pragma unroll
  for (int m = 0; m < MREP; m++)
#pragma unroll
    for (int n = 0; n < 4; n++) acc[m][n] = (f32x4){0.f, 0.f, 0.f, 0.f};

  auto stage = [&](int buf, int kt) {
    unsigned short* ab = &As[buf][0];
    unsigned short* bb = &Bs[buf][0];
    lds_load16(A1 + (long)(row0 + sr0) * lda1 + kt + sc0, ab + t * 8);
    if constexpr (MREP == 4)
      lds_load16(A1 + (long)(row0 + sr0 + 64) * lda1 + kt + sc0, ab + t * 8 + 2048);
    lds_load16(Bt1 + (long)(col0 + sr0) * K1 + kt + sc0, bb + t * 8);
    lds_load16(Bt1 + (long)(col0 + sr0 + 64) * K1 + kt + sc0, bb + t * 8 + 2048);
  };

  stage(0, 0);
  __syncthreads();
  int cur = 0;
  for (int kt = 0; kt < K1; kt += 32) {
    if (kt + 32 < K1) stage(cur ^ 1, kt + 32);
    bf16x8 af[MREP], bfv[4];
#pragma unroll
    for (int m = 0; m < MREP; m++)
      af[m] = *(const bf16x8*)&As[cur][(wr * (MREP * 16) + m * 16 + rl) * 32 + kswz * 8];
#pragma unroll
    for (int n = 0; n < 4; n++)
      bfv[n] = *(const bf16x8*)&Bs[cur][(wc * 64 + n * 16 + rl) * 32 + kswz * 8];
    __builtin_amdgcn_s_setprio(1);
#pragma unroll
    for (int m = 0; m < MREP; m++)
#pragma unroll
      for (int n = 0; n < 4; n++)
        acc[m][n] = __builtin_amdgcn_mfma_f32_16x16x32_bf16(af[m], bfv[n], acc[m][n], 0, 0, 0);
    __builtin_amdgcn_s_setprio(0);
    __syncthreads();
    cur ^= 1;
  }

#pragma unroll
  for (int m = 0; m < MREP; m++)
#pragma unroll
    for (int n = 0; n < 4; n++)
#pragma unroll
      for (int j = 0; j < 4; j++) {
        int row = row0 + wr * (MREP * 16) + m * 16 + kg * 4 + j;
        int col = col0 + wc * 64 + n * 16 + rl;
        float v = acc[m][n][j] * gate[row * 8 + (col >> 4)];
        ((unsigned short*)outp)[(long)row * ldout + col] = f2b(v);
      }
}

// ---------------- 8-phase 256-row GEMM (main GEMMs) ----------------
// BM=256, BK=64, 512 threads = 8 waves (2 M x 4 N). BN = NREP*64.
// K split: (A1/Bt1, K1) then (A2/Bt2, K2); both multiples of 64.
// 4 phases per K-tile: {ds_read quadrant || stage 1 half-tile of next} ->
// barrier -> lgkmcnt(0) -> MFMA quadrant -> barrier. Counted vmcnt(2) once
// per tile (allows next tile's A-lo in flight); vmcnt(0) only at last tile.
// LDS swizzle: 16B chunk c of row r stored at c ^ (r&7); applied as
// pre-swizzled global source (linear global_load_lds dest) + swizzled ds_read.
template<int MODE, int NREP>
__global__ __launch_bounds__(512, 2)
void gemm8(const unsigned short* __restrict__ A1, int lda1, int K1,
           const unsigned short* __restrict__ A2, int lda2, int K2,
           const unsigned short* __restrict__ Bt1, int ldb1,
           const unsigned short* __restrict__ Bt2, int ldb2,
           const float* __restrict__ bias,
           void* __restrict__ outp, int ldout) {
  constexpr int BN = NREP * 64;
  constexpr int ABUF = 256 * 64;   // ushorts per A k-tile buffer (32KB)
  constexpr int BBUF = BN * 64;
  constexpr int NH = NREP / 2;
  __shared__ __attribute__((aligned(16))) unsigned short lds[2 * ABUF + 2 * BBUF];

  const int t = threadIdx.x;
  const int lane = t & 63, wave = t >> 6;
  const int wr = wave >> 2, wc = wave & 3;           // 2 x 4 wave grid
  const int rl = lane & 15, kg = lane >> 4;
  const int row0 = blockIdx.x * 256, col0 = blockIdx.y * BN;
  const int srow = t >> 3;                           // 0..63
  const int sk = ((t & 7) ^ (srow & 7)) * 8;         // pre-swizzled source k

  f32x4 acc[8][NREP];
#pragma unroll
  for (int m = 0; m < 8; m++)
#pragma unroll
    for (int n = 0; n < NREP; n++) acc[m][n] = (f32x4){0.f, 0.f, 0.f, 0.f};

  auto stageA = [&](int buf, int h, int kt) {
    const unsigned short* src; long ld; int kl;
    if (kt < K1) { src = A1; ld = lda1; kl = kt; }
    else         { src = A2; ld = lda2; kl = kt - K1; }
    const unsigned short* s0 = src + (long)(row0 + h * 128 + srow) * ld + kl + sk;
    unsigned short* d = &lds[buf * ABUF + h * 8192 + t * 8];
    lds_load16(s0, d);
    lds_load16(s0 + 64 * ld, d + 4096);
  };
  auto stageB = [&](int buf, int h, int kt) {
    const unsigned short* src; long ld; int kl;
    if (kt < K1) { src = Bt1; ld = ldb1; kl = kt; }
    else         { src = Bt2; ld = ldb2; kl = kt - K1; }
    const unsigned short* s0 = src + (long)(col0 + h * (BN / 2) + srow) * ld + kl + sk;
    unsigned short* d = &lds[2 * ABUF + buf * BBUF + h * (BBUF / 2) + t * 8];
    lds_load16(s0, d);
    if constexpr (NREP == 4) lds_load16(s0 + 64 * ld, d + 4096);
  };
  auto ldA = [&](int cur, int mh, int m, int ks) {
    int r = mh * 64 + m * 16 + rl;
    int cp = (ks * 4 + kg) ^ (rl & 7);
    return *(const bf16x8*)&lds[cur * ABUF + wr * 8192 + r * 64 + cp * 8];
  };
  auto ldB = [&](int cur, int n, int ks) {
    int c = (wc & 1) * (16 * NREP) + n * 16 + rl;
    int cp = (ks * 4 + kg) ^ (rl & 7);
    return *(const bf16x8*)&lds[2 * ABUF + cur * BBUF + (wc >> 1) * (BBUF / 2) + c * 64 + cp * 8];
  };

  const int Ktot = K1 + K2;
  bf16x8 Af[8], Bf[2 * NREP];

  // prologue: stage tile 0 fully
  stageA(0, 0, 0); stageA(0, 1, 0); stageB(0, 0, 0); stageB(0, 1, 0);

  int cur = 0;
  for (int kt = 0; kt < Ktot; kt += 64) {
    const int nxt = cur ^ 1;
    const bool pf = (kt + 64 < Ktot);
    // ---- phase 0: quadrant (m-lo, n-lo) ----
    if (pf) {
      stageA(nxt, 0, kt + 64);
      asm volatile("s_waitcnt vmcnt(2)" ::: "memory");   // drain all of tile t; allow next A-lo
    } else {
      asm volatile("s_waitcnt vmcnt(0)" ::: "memory");
    }
    __builtin_amdgcn_s_barrier();                        // tile t visible to all waves
#pragma unroll
    for (int m = 0; m < 4; m++) { Af[m*2] = ldA(cur, 0, m, 0); Af[m*2+1] = ldA(cur, 0, m, 1); }
#pragma unroll
    for (int n = 0; n < NH; n++) { Bf[n*2] = ldB(cur, n, 0); Bf[n*2+1] = ldB(cur, n, 1); }
    asm volatile("s_waitcnt lgkmcnt(0)" ::: "memory");
    __builtin_amdgcn_sched_barrier(0);
    __builtin_amdgcn_s_setprio(1);
#pragma unroll
    for (int m = 0; m < 4; m++)
#pragma unroll
      for (int n = 0; n < NH; n++) {
        acc[m][n] = __builtin_amdgcn_mfma_f32_16x16x32_bf16(Af[m*2],   Bf[n*2],   acc[m][n], 0, 0, 0);
        acc[m][n] = __builtin_amdgcn_mfma_f32_16x16x32_bf16(Af[m*2+1], Bf[n*2+1], acc[m][n], 0, 0, 0);
      }
    __builtin_amdgcn_s_setprio(0);
    __builtin_amdgcn_s_barrier();
    // ---- phase 1: quadrant (m-lo, n-hi) ----
#pragma unroll
    for (int n = NH; n < NREP; n++) { Bf[n*2] = ldB(cur, n, 0); Bf[n*2+1] = ldB(cur, n, 1); }
    if (pf) stageB(nxt, 0, kt + 64);
    __builtin_amdgcn_s_barrier();
    asm volatile("s_waitcnt lgkmcnt(0)" ::: "memory");
    __builtin_amdgcn_sched_barrier(0);
    __builtin_amdgcn_s_setprio(1);
#pragma unroll
    for (int m = 0; m < 4; m++)
#pragma unroll
      for (int n = NH; n < NREP; n++) {
        acc[m][n] = __builtin_amdgcn_mfma_f32_16x16x32_bf16(Af[m*2],   Bf[n*2],   acc[m][n], 0, 0, 0);
        acc[m][n] = __builtin_amdgcn_mfma_f32_16x16x32_bf16(Af[m*2+1], Bf[n*2+1], acc[m][n], 0, 0, 0);
      }
    __builtin_amdgcn_s_setprio(0);
    __builtin_amdgcn_s_barrier();
    // ---- phase 2: quadrant (m-hi, n-lo) ----
#pragma unroll
    for (int m = 0; m < 4; m++) { Af[m*2] = ldA(cur, 1, m, 0); Af[m*2+1] = ldA(cur, 1, m, 1); }
    if (pf) stageB(nxt, 1, kt + 64);
    __builtin_amdgcn_s_barrier();
    asm volatile("s_waitcnt lgkmcnt(0)" ::: "memory");
    __builtin_amdgcn_sched_barrier(0);
    __builtin_amdgcn_s_setprio(1);
#pragma unroll
    for (int m = 0; m < 4; m++)
#pragma unroll
      for (int n = 0; n < NH; n++) {
        acc[4+m][n] = __builtin_amdgcn_mfma_f32_16x16x32_bf16(Af[m*2],   Bf[n*2],   acc[4+m][n], 0, 0, 0);
        acc[4+m][n] = __builtin_amdgcn_mfma_f32_16x16x32_bf16(Af[m*2+1], Bf[n*2+1], acc[4+m][n], 0, 0, 0);
      }
    __builtin_amdgcn_s_setprio(0);
    __builtin_amdgcn_s_barrier();
    // ---- phase 3: quadrant (m-hi, n-hi) ----
    if (pf) stageA(nxt, 1, kt + 64);
    __builtin_amdgcn_s_barrier();
    __builtin_amdgcn_s_setprio(1);
#pragma unroll
    for (int m = 0; m < 4; m++)
#pragma unroll
      for (int n = NH; n < NREP; n++) {
        acc[4+m][n] = __builtin_amdgcn_mfma_f32_16x16x32_bf16(Af[m*2],   Bf[n*2],   acc[4+m][n], 0, 0, 0);
        acc[4+m][n] = __builtin_amdgcn_mfma_f32_16x16x32_bf16(Af[m*2+1], Bf[n*2+1], acc[4+m][n], 0, 0, 0);
      }
    __builtin_amdgcn_s_setprio(0);
    __builtin_amdgcn_s_barrier();
    cur = nxt;
  }

  // epilogue
#pragma unroll
  for (int m = 0; m < 8; m++)
#pragma unroll
    for (int n = 0; n < NREP; n++)
#pragma unroll
      for (int j = 0; j < 4; j++) {
        int row = row0 + wr * 128 + m * 16 + kg * 4 + j;
        int col = col0 + wc * (16 * NREP) + n * 16 + rl;
        float v = acc[m][n][j] + bias[col];
        v = fmaxf(v, 0.f);
        if (MODE == 1) ((unsigned short*)outp)[(long)row * ldout + col] = f2b(v);
        else           ((float*)outp)[(long)row * ldout + col] = v;
      }
}

// ---------------- launch ----------------

extern "C" void kernel_launch(void* const* d_in, const int* in_sizes, int n_in,
                              void* d_out, int out_size, void* d_ws, size_t ws_size,
                              hipStream_t stream) {
  (void)in_sizes; (void)n_in; (void)out_size; (void)ws_size;
  const float* dnn = (const float*)d_in[0];
  const int*   dom = (const int*)d_in[1];
  const float* emb = (const float*)d_in[2];
  const float* gW  = (const float*)d_in[3];
  const float* gb  = (const float*)d_in[4];
  const float* Wm[3]  = {(const float*)d_in[5],  (const float*)d_in[10], (const float*)d_in[15]};
  const float* bm[3]  = {(const float*)d_in[6],  (const float*)d_in[11], (const float*)d_in[16]};
  const float* Am[3]  = {(const float*)d_in[7],  (const float*)d_in[12], (const float*)d_in[17]};
  const float* Bm[3]  = {(const float*)d_in[8],  (const float*)d_in[13], (const float*)d_in[18]};
  const float* lbm[3] = {(const float*)d_in[9],  (const float*)d_in[14], (const float*)d_in[19]};

  const int M = M_ROWS;
  const int dIn[3]  = {1024, 1024, 512};
  const int dOutN[3] = {1024, 512, 256};

  char* p = (char*)d_ws;
  auto carve = [&](size_t bytes) { char* r = p; p += (bytes + 255) & ~(size_t)255; return r; };
  float* gate = (float*)carve((size_t)M * 8 * sizeof(float));
  unsigned short* xb0 = (unsigned short*)carve((size_t)M * 1024 * 2);
  unsigned short* xb1 = (unsigned short*)carve((size_t)M * 1024 * 2);
  unsigned short* tg  = (unsigned short*)carve((size_t)M * KAUG * 2);
  unsigned short *Wt[3], *Aft[3], *Bft[3];
  for (int l = 0; l < 3; l++) {
    Wt[l]  = (unsigned short*)carve((size_t)dOutN[l] * dIn[l] * 2);
    Aft[l] = (unsigned short*)carve((size_t)128 * dIn[l] * 2);
    Bft[l] = (unsigned short*)carve((size_t)dOutN[l] * KAUG * 2);
  }

  gate_kernel<<<M / 256, 256, 0, stream>>>(dom, emb, gW, gb, gate);
  {
    int n4 = M * 1024 / 4;
    f32_to_bf16_vec<<<(n4 + 255) / 256, 256, 0, stream>>>(dnn, xb0, n4);
  }
  for (int l = 0; l < 3; l++) {
    long totW = (long)dOutN[l] * dIn[l];
    build_wt<<<(int)((totW + 255) / 256), 256, 0, stream>>>(Wm[l], Wt[l], dIn[l], dOutN[l], totW);
    long totA = (long)128 * dIn[l];
    build_aft<<<(int)((totA + 255) / 256), 256, 0, stream>>>(Am[l], Aft[l], dIn[l], totA);
    long totB = (long)dOutN[l] * KAUG;
    build_bft<<<(int)((totB + 255) / 256), 256, 0, stream>>>(Bm[l], lbm[l], Bft[l], dOutN[l], totB);
  }
  aug_fill<<<(M * 64) / 256, 256, 0, stream>>>(gate, tg);

  const unsigned short* xin = xb0;
  for (int l = 0; l < 3; l++) {
    int K1 = dIn[l], N = dOutN[l];
    // tg[:, :128] = gate-scaled x @ A_flat   (64-row tiles -> 256 blocks)
    gemm2ph<0, 2><<<dim3(M / 64, 1), 256, 0, stream>>>(
        xin, K1, K1, Aft[l], gate, (void*)tg, KAUG);
    // out = relu(x @ W + tg_aug @ B_aug + bias)  -- 8-phase 256-row kernel
    if (l == 0)
      gemm8<1, 4><<<dim3(M / 256, N / 256), 512, 0, stream>>>(
          xin, K1, K1, tg, KAUG, KAUG, Wt[l], K1, Bft[l], KAUG, bm[l], (void*)xb1, N);
    else if (l == 1)
      gemm8<1, 2><<<dim3(M / 256, N / 128), 512, 0, stream>>>(
          xin, K1, K1, tg, KAUG, KAUG, Wt[l], K1, Bft[l], KAUG, bm[l], (void*)xb0, N);
    else
      gemm8<2, 2><<<dim3(M / 256, N / 128), 512, 0, stream>>>(
          xin, K1, K1, tg, KAUG, KAUG, Wt[l], K1, Bft[l], KAUG, bm[l], d_out, N);
    xin = (l == 0) ? xb1 : xb0;
  }
}

// Round 4
// 188.571 us; speedup vs baseline: 1.2047x; 1.0588x over previous
//
#include <hip/hip_runtime.h>
#include <hip/hip_bf16.h>
#include <stdint.h>

#define KAUG 160   // 128 LoRA cols + 8 gate cols + 24 zero pad (multiple of 32)
#define M_ROWS 16384

typedef __attribute__((ext_vector_type(8))) __bf16 bf16x8;
typedef __attribute__((ext_vector_type(4))) float f32x4;

__device__ __forceinline__ unsigned short f2b(float f) {
  unsigned int u = __builtin_bit_cast(unsigned int, f);
  u = (u + 0x7fffu + ((u >> 16) & 1u)) >> 16;
  return (unsigned short)u;
}

__device__ __forceinline__ void lds_load16(const unsigned short* g, unsigned short* l) {
  __builtin_amdgcn_global_load_lds(
      (const __attribute__((address_space(1))) void*)g,
      (__attribute__((address_space(3))) void*)l, 16, 0, 0);
}

// ---------------- prep kernels ----------------

__global__ void gate_kernel(const int* __restrict__ dom, const float* __restrict__ emb,
                            const float* __restrict__ gW, const float* __restrict__ gb,
                            float* __restrict__ gate) {
  int i = blockIdx.x * blockDim.x + threadIdx.x;
  int d = dom[i];
  float e0 = emb[d*4+0], e1 = emb[d*4+1], e2 = emb[d*4+2], e3 = emb[d*4+3];
  float l[8]; float mx = -1e30f;
#pragma unroll
  for (int j = 0; j < 8; j++) {
    l[j] = e0*gW[j] + e1*gW[8+j] + e2*gW[16+j] + e3*gW[24+j] + gb[j];
    mx = fmaxf(mx, l[j]);
  }
  float s = 0.f;
#pragma unroll
  for (int j = 0; j < 8; j++) { l[j] = __expf(l[j] - mx); s += l[j]; }
  float inv = 1.0f / s;
#pragma unroll
  for (int j = 0; j < 8; j++) gate[i*8+j] = l[j] * inv;
}

__global__ void f32_to_bf16_vec(const float* __restrict__ in, unsigned short* __restrict__ out, int n4) {
  int i = blockIdx.x * blockDim.x + threadIdx.x;
  if (i >= n4) return;
  float4 v = ((const float4*)in)[i];
  ushort4 o;
  o.x = f2b(v.x); o.y = f2b(v.y); o.z = f2b(v.z); o.w = f2b(v.w);
  ((ushort4*)out)[i] = o;
}

// LDS-tiled transpose: Wt[n*K+k] = bf16(W[k*N+n]); both sides coalesced.
__global__ void build_wt_t(const float* __restrict__ W, unsigned short* __restrict__ Wt,
                           int K, int N) {
  __shared__ float tl[32][33];
  int n0 = blockIdx.x * 32, k0 = blockIdx.y * 32;
  int tx = threadIdx.x & 31, ty = threadIdx.x >> 5;   // 256 thr: ty 0..7
#pragma unroll
  for (int i = 0; i < 32; i += 8)
    tl[ty + i][tx] = W[(long)(k0 + ty + i) * N + n0 + tx];
  __syncthreads();
#pragma unroll
  for (int i = 0; i < 32; i += 8)
    Wt[(long)(n0 + ty + i) * K + k0 + tx] = f2b(tl[tx][ty + i]);
}

// Aft[(e*16+r)*P + p] = bf16(A[e][p][r]); LDS-tiled, coalesced.
__global__ void build_aft_t(const float* __restrict__ A, unsigned short* __restrict__ Aft, int P) {
  __shared__ float tl[64][17];
  int e = blockIdx.y; long p0 = (long)blockIdx.x * 64;
  int t = threadIdx.x;
#pragma unroll
  for (int pass = 0; pass < 4; pass++) {
    int idx = t + pass * 256;           // 0..1023
    int pl = idx >> 4, r = idx & 15;
    tl[pl][r] = A[((long)e * P + p0 + pl) * 16 + r];
  }
  __syncthreads();
#pragma unroll
  for (int pass = 0; pass < 4; pass++) {
    int idx = t + pass * 256;
    int r = idx >> 6, pl = idx & 63;
    Aft[(long)(e * 16 + r) * P + p0 + pl] = f2b(tl[pl][r]);
  }
}

// Bft[n*KAUG + kk]: kk<128 -> B_flat[kk*H+n]; kk in [128,136) -> lb[kk-128][n]; else 0.
__global__ void build_bft_t(const float* __restrict__ Bm, const float* __restrict__ lb,
                            unsigned short* __restrict__ Bft, int H) {
  __shared__ float tl[32][33];
  int n0 = blockIdx.x * 32, kk0 = blockIdx.y * 32;
  int tx = threadIdx.x & 31, ty = threadIdx.x >> 5;
#pragma unroll
  for (int i = 0; i < 32; i += 8) {
    int kk = kk0 + ty + i;
    float v;
    if (kk < 128)       v = Bm[(long)kk * H + n0 + tx];
    else if (kk < 136)  v = lb[(long)(kk - 128) * H + n0 + tx];
    else                v = 0.f;
    tl[ty + i][tx] = v;
  }
  __syncthreads();
#pragma unroll
  for (int i = 0; i < 32; i += 8)
    Bft[(long)(n0 + ty + i) * KAUG + kk0 + tx] = f2b(tl[tx][ty + i]);
}

// tg[b][128+j]: j<8 -> gate[b][j]; j in [8,32) -> 0
__global__ void aug_fill(const float* __restrict__ gate, unsigned short* __restrict__ tg) {
  int i = blockIdx.x * blockDim.x + threadIdx.x;  // M*32 threads
  int j = i & 31; int b = i >> 5;
  float v = (j < 8) ? gate[b*8 + j] : 0.f;
  tg[(long)b * KAUG + 128 + j] = f2b(v);
}

// ---------------- 2-phase 64-row GEMM (x@A only, MODE 0) ----------------
template<int MREP>
__global__ __launch_bounds__(256)
void gemm2ph(const unsigned short* __restrict__ A1, int lda1, int K1,
             const unsigned short* __restrict__ Bt1,
             const float* __restrict__ gate,
             void* __restrict__ outp, int ldout) {
  constexpr int BM = MREP * 32;
  __shared__ __attribute__((aligned(16))) unsigned short As[2][BM * 32];
  __shared__ __attribute__((aligned(16))) unsigned short Bs[2][128 * 32];
  const int t = threadIdx.x;
  const int lane = t & 63, wave = t >> 6;
  const int wr = wave >> 1, wc = wave & 1;
  const int row0 = blockIdx.x * BM, col0 = blockIdx.y * 128;
  const int rl = lane & 15, kg = lane >> 4;
  const int kswz = kg ^ ((rl >> 1) & 3);
  const int sr0 = t >> 2;
  const int sc0 = (((t & 3) ^ ((sr0 >> 1) & 3))) * 8;

  f32x4 acc[MREP][4];
#pragma unroll
  for (int m = 0; m < MREP; m++)
#pragma unroll
    for (int n = 0; n < 4; n++) acc[m][n] = (f32x4){0.f, 0.f, 0.f, 0.f};

  auto stage = [&](int buf, int kt) {
    unsigned short* ab = &As[buf][0];
    unsigned short* bb = &Bs[buf][0];
    lds_load16(A1 + (long)(row0 + sr0) * lda1 + kt + sc0, ab + t * 8);
    if constexpr (MREP == 4)
      lds_load16(A1 + (long)(row0 + sr0 + 64) * lda1 + kt + sc0, ab + t * 8 + 2048);
    lds_load16(Bt1 + (long)(col0 + sr0) * K1 + kt + sc0, bb + t * 8);
    lds_load16(Bt1 + (long)(col0 + sr0 + 64) * K1 + kt + sc0, bb + t * 8 + 2048);
  };

  stage(0, 0);
  __syncthreads();
  int cur = 0;
  for (int kt = 0; kt < K1; kt += 32) {
    if (kt + 32 < K1) stage(cur ^ 1, kt + 32);
    bf16x8 af[MREP], bfv[4];
#pragma unroll
    for (int m = 0; m < MREP; m++)
      af[m] = *(const bf16x8*)&As[cur][(wr * (MREP * 16) + m * 16 + rl) * 32 + kswz * 8];
#pragma unroll
    for (int n = 0; n < 4; n++)
      bfv[n] = *(const bf16x8*)&Bs[cur][(wc * 64 + n * 16 + rl) * 32 + kswz * 8];
    __builtin_amdgcn_s_setprio(1);
#pragma unroll
    for (int m = 0; m < MREP; m++)
#pragma unroll
      for (int n = 0; n < 4; n++)
        acc[m][n] = __builtin_amdgcn_mfma_f32_16x16x32_bf16(af[m], bfv[n], acc[m][n], 0, 0, 0);
    __builtin_amdgcn_s_setprio(0);
    __syncthreads();
    cur ^= 1;
  }

#pragma unroll
  for (int m = 0; m < MREP; m++)
#pragma unroll
    for (int n = 0; n < 4; n++)
#pragma unroll
      for (int j = 0; j < 4; j++) {
        int row = row0 + wr * (MREP * 16) + m * 16 + kg * 4 + j;
        int col = col0 + wc * 64 + n * 16 + rl;
        float v = acc[m][n][j] * gate[row * 8 + (col >> 4)];
        ((unsigned short*)outp)[(long)row * ldout + col] = f2b(v);
      }
}

// ---------------- deep-pipelined main GEMM ----------------
// BM=256, BN=NREP*64, BK=32, 4 LDS buffers, 512 threads = 8 waves (2M x 4N).
// Pipeline: prologue stages tiles 0,1,2; tile t body:
//   vmcnt(2L) [L=loads/thread/tile] -> s_barrier -> stage(t+3) ->
//   ds_read all frags -> lgkmcnt(0) -> 32*NREP/4 MFMA (setprio).
// Tile t's loads issued 3 tiles (~3 full MFMA phases) before use; wait never
// drains in-flight prefetch (counted vmcnt, T4). One barrier per tile.
// LDS swizzle: 16B chunk c of row r stored at chunk c^(r&3); applied as
// pre-swizzled global source (linear global_load_lds dest) + swizzled ds_read.
template<int MODE, int NREP>
__global__ __launch_bounds__(512, 2)
void gemm8(const unsigned short* __restrict__ A1, int lda1, int K1,
           const unsigned short* __restrict__ A2, int lda2, int K2,
           const unsigned short* __restrict__ Bt1, int ldb1,
           const unsigned short* __restrict__ Bt2, int ldb2,
           const float* __restrict__ bias,
           void* __restrict__ outp, int ldout) {
  constexpr int BN = NREP * 64;
  constexpr int ATILE = 256 * 32;          // ushorts per A buffer (16KB)
  constexpr int BTILE = BN * 32;           // ushorts per B buffer
  __shared__ __attribute__((aligned(16))) unsigned short lds[4 * ATILE + 4 * BTILE];

  const int t = threadIdx.x;
  const int lane = t & 63, wave = t >> 6;
  const int wr = wave >> 2, wc = wave & 3;            // 2 x 4 wave grid
  const int rl = lane & 15, kg = lane >> 4;
  const int row0 = blockIdx.x * 256, col0 = blockIdx.y * BN;

  // staging: thread covers 16B chunk ids t (and t+512 for 256-row operands)
  const int sr = t >> 2;                              // chunk row
  const int sg = ((t & 3) ^ (sr & 3)) * 8;            // pre-swizzled source k (elems)

  f32x4 acc[8][NREP];
#pragma unroll
  for (int m = 0; m < 8; m++)
#pragma unroll
    for (int n = 0; n < NREP; n++) acc[m][n] = (f32x4){0.f, 0.f, 0.f, 0.f};

  auto stageA = [&](int buf, int kt) {
    const unsigned short* src; long ld; int kl;
    if (kt < K1) { src = A1; ld = lda1; kl = kt; }
    else         { src = A2; ld = lda2; kl = kt - K1; }
    unsigned short* d = &lds[buf * ATILE + t * 8];
    lds_load16(src + (long)(row0 + sr) * ld + kl + sg, d);
    lds_load16(src + (long)(row0 + sr + 128) * ld + kl + sg, d + 4096);
  };
  auto stageB = [&](int buf, int kt) {
    const unsigned short* src; long ld; int kl;
    if (kt < K1) { src = Bt1; ld = ldb1; kl = kt; }
    else         { src = Bt2; ld = ldb2; kl = kt - K1; }
    unsigned short* d = &lds[4 * ATILE + buf * BTILE + t * 8];
    if constexpr (NREP == 4) {
      lds_load16(src + (long)(col0 + sr) * ld + kl + sg, d);
      lds_load16(src + (long)(col0 + sr + 128) * ld + kl + sg, d + 4096);
    } else {
      if (t < 512) {  // BN=128: 512 chunks, one per thread
        lds_load16(src + (long)(col0 + sr) * ld + kl + sg, d);
      }
    }
  };

  const int Ktot = K1 + K2;
  const int NT = Ktot / 32;

  // prologue: 3 tiles in flight
  stageA(0, 0);  stageB(0, 0);
  stageA(1, 32); stageB(1, 32);
  stageA(2, 64); stageB(2, 64);

  for (int tt = 0; tt < NT; ++tt) {
    // counted wait: allow stages of tiles tt+1, tt+2 to stay in flight
    if (tt + 2 < NT) {
      if constexpr (NREP == 4) asm volatile("s_waitcnt vmcnt(8)" ::: "memory");
      else                     asm volatile("s_waitcnt vmcnt(6)" ::: "memory");
    } else if (tt + 1 < NT) {
      if constexpr (NREP == 4) asm volatile("s_waitcnt vmcnt(4)" ::: "memory");
      else                     asm volatile("s_waitcnt vmcnt(3)" ::: "memory");
    } else {
      asm volatile("s_waitcnt vmcnt(0)" ::: "memory");
    }
    __builtin_amdgcn_s_barrier();          // tile tt visible to all waves
    __builtin_amdgcn_sched_barrier(0);     // pin: nothing crosses the barrier
    const int cur = tt & 3;
    if (tt + 3 < NT) {                     // prefetch tile tt+3 (post-barrier: buffer safe)
      stageA((tt + 3) & 3, (tt + 3) * 32);
      stageB((tt + 3) & 3, (tt + 3) * 32);
    }
    bf16x8 Af[8], Bf[NREP];
#pragma unroll
    for (int m = 0; m < 8; m++) {
      int r = wr * 128 + m * 16 + rl;
      Af[m] = *(const bf16x8*)&lds[cur * ATILE + r * 32 + (kg ^ (rl & 3)) * 8];
    }
#pragma unroll
    for (int n = 0; n < NREP; n++) {
      int c = wc * (16 * NREP) + n * 16 + rl;
      Bf[n] = *(const bf16x8*)&lds[4 * ATILE + cur * BTILE + c * 32 + (kg ^ (rl & 3)) * 8];
    }
    asm volatile("s_waitcnt lgkmcnt(0)" ::: "memory");
    __builtin_amdgcn_sched_barrier(0);
    __builtin_amdgcn_s_setprio(1);
#pragma unroll
    for (int m = 0; m < 8; m++)
#pragma unroll
      for (int n = 0; n < NREP; n++)
        acc[m][n] = __builtin_amdgcn_mfma_f32_16x16x32_bf16(Af[m], Bf[n], acc[m][n], 0, 0, 0);
    __builtin_amdgcn_s_setprio(0);
  }

  // epilogue
#pragma unroll
  for (int m = 0; m < 8; m++)
#pragma unroll
    for (int n = 0; n < NREP; n++)
#pragma unroll
      for (int j = 0; j < 4; j++) {
        int row = row0 + wr * 128 + m * 16 + kg * 4 + j;
        int col = col0 + wc * (16 * NREP) + n * 16 + rl;
        float v = acc[m][n][j] + bias[col];
        v = fmaxf(v, 0.f);
        if (MODE == 1) ((unsigned short*)outp)[(long)row * ldout + col] = f2b(v);
        else           ((float*)outp)[(long)row * ldout + col] = v;
      }
}

// ---------------- launch ----------------

extern "C" void kernel_launch(void* const* d_in, const int* in_sizes, int n_in,
                              void* d_out, int out_size, void* d_ws, size_t ws_size,
                              hipStream_t stream) {
  (void)in_sizes; (void)n_in; (void)out_size; (void)ws_size;
  const float* dnn = (const float*)d_in[0];
  const int*   dom = (const int*)d_in[1];
  const float* emb = (const float*)d_in[2];
  const float* gW  = (const float*)d_in[3];
  const float* gb  = (const float*)d_in[4];
  const float* Wm[3]  = {(const float*)d_in[5],  (const float*)d_in[10], (const float*)d_in[15]};
  const float* bm[3]  = {(const float*)d_in[6],  (const float*)d_in[11], (const float*)d_in[16]};
  const float* Am[3]  = {(const float*)d_in[7],  (const float*)d_in[12], (const float*)d_in[17]};
  const float* Bm[3]  = {(const float*)d_in[8],  (const float*)d_in[13], (const float*)d_in[18]};
  const float* lbm[3] = {(const float*)d_in[9],  (const float*)d_in[14], (const float*)d_in[19]};

  const int M = M_ROWS;
  const int dIn[3]  = {1024, 1024, 512};
  const int dOutN[3] = {1024, 512, 256};

  char* p = (char*)d_ws;
  auto carve = [&](size_t bytes) { char* r = p; p += (bytes + 255) & ~(size_t)255; return r; };
  float* gate = (float*)carve((size_t)M * 8 * sizeof(float));
  unsigned short* xb0 = (unsigned short*)carve((size_t)M * 1024 * 2);
  unsigned short* xb1 = (unsigned short*)carve((size_t)M * 1024 * 2);
  unsigned short* tg  = (unsigned short*)carve((size_t)M * KAUG * 2);
  unsigned short *Wt[3], *Aft[3], *Bft[3];
  for (int l = 0; l < 3; l++) {
    Wt[l]  = (unsigned short*)carve((size_t)dOutN[l] * dIn[l] * 2);
    Aft[l] = (unsigned short*)carve((size_t)128 * dIn[l] * 2);
    Bft[l] = (unsigned short*)carve((size_t)dOutN[l] * KAUG * 2);
  }

  gate_kernel<<<M / 256, 256, 0, stream>>>(dom, emb, gW, gb, gate);
  {
    int n4 = M * 1024 / 4;
    f32_to_bf16_vec<<<(n4 + 255) / 256, 256, 0, stream>>>(dnn, xb0, n4);
  }
  for (int l = 0; l < 3; l++) {
    build_wt_t<<<dim3(dOutN[l] / 32, dIn[l] / 32), 256, 0, stream>>>(Wm[l], Wt[l], dIn[l], dOutN[l]);
    build_aft_t<<<dim3(dIn[l] / 64, 8), 256, 0, stream>>>(Am[l], Aft[l], dIn[l]);
    build_bft_t<<<dim3(dOutN[l] / 32, KAUG / 32), 256, 0, stream>>>(Bm[l], lbm[l], Bft[l], dOutN[l]);
  }
  aug_fill<<<(M * 32) / 256, 256, 0, stream>>>(gate, tg);

  const unsigned short* xin = xb0;
  for (int l = 0; l < 3; l++) {
    int K1 = dIn[l], N = dOutN[l];
    // tg[:, :128] = gate-scaled x @ A_flat   (64-row tiles -> 256 blocks)
    gemm2ph<2><<<dim3(M / 64, 1), 256, 0, stream>>>(
        xin, K1, K1, Aft[l], gate, (void*)tg, KAUG);
    // out = relu(x @ W + tg_aug @ B_aug + bias)  -- deep-pipelined kernel
    if (l == 0)
      gemm8<1, 4><<<dim3(M / 256, N / 256), 512, 0, stream>>>(
          xin, K1, K1, tg, KAUG, KAUG, Wt[l], K1, Bft[l], KAUG, bm[l], (void*)xb1, N);
    else if (l == 1)
      gemm8<1, 2><<<dim3(M / 256, N / 128), 512, 0, stream>>>(
          xin, K1, K1, tg, KAUG, KAUG, Wt[l], K1, Bft[l], KAUG, bm[l], (void*)xb0, N);
    else
      gemm8<2, 2><<<dim3(M / 256, N / 128), 512, 0, stream>>>(
          xin, K1, K1, tg, KAUG, KAUG, Wt[l], K1, Bft[l], KAUG, bm[l], d_out, N);
    xin = (l == 0) ? xb1 : xb0;
  }
}

// Round 5
// 185.294 us; speedup vs baseline: 1.2260x; 1.0177x over previous
//
#include <hip/hip_runtime.h>
#include <hip/hip_bf16.h>
#include <stdint.h>

#define KAUG 192   // 128 LoRA cols + 8 gate cols + 56 zero pad (multiple of 64)
#define M_ROWS 16384

typedef __attribute__((ext_vector_type(8))) __bf16 bf16x8;
typedef __attribute__((ext_vector_type(4))) float f32x4;

__device__ __forceinline__ unsigned short f2b(float f) {
  unsigned int u = __builtin_bit_cast(unsigned int, f);
  u = (u + 0x7fffu + ((u >> 16) & 1u)) >> 16;
  return (unsigned short)u;
}

__device__ __forceinline__ void lds_load16(const unsigned short* g, unsigned short* l) {
  __builtin_amdgcn_global_load_lds(
      (const __attribute__((address_space(1))) void*)g,
      (__attribute__((address_space(3))) void*)l, 16, 0, 0);
}

// ---------------- prep kernels ----------------

__global__ void gate_kernel(const int* __restrict__ dom, const float* __restrict__ emb,
                            const float* __restrict__ gW, const float* __restrict__ gb,
                            float* __restrict__ gate) {
  int i = blockIdx.x * blockDim.x + threadIdx.x;
  int d = dom[i];
  float e0 = emb[d*4+0], e1 = emb[d*4+1], e2 = emb[d*4+2], e3 = emb[d*4+3];
  float l[8]; float mx = -1e30f;
#pragma unroll
  for (int j = 0; j < 8; j++) {
    l[j] = e0*gW[j] + e1*gW[8+j] + e2*gW[16+j] + e3*gW[24+j] + gb[j];
    mx = fmaxf(mx, l[j]);
  }
  float s = 0.f;
#pragma unroll
  for (int j = 0; j < 8; j++) { l[j] = __expf(l[j] - mx); s += l[j]; }
  float inv = 1.0f / s;
#pragma unroll
  for (int j = 0; j < 8; j++) gate[i*8+j] = l[j] * inv;
}

__global__ void f32_to_bf16_vec(const float* __restrict__ in, unsigned short* __restrict__ out, int n4) {
  int i = blockIdx.x * blockDim.x + threadIdx.x;
  if (i >= n4) return;
  float4 v = ((const float4*)in)[i];
  ushort4 o;
  o.x = f2b(v.x); o.y = f2b(v.y); o.z = f2b(v.z); o.w = f2b(v.w);
  ((ushort4*)out)[i] = o;
}

// LDS-tiled transpose: Wt[n*K+k] = bf16(W[k*N+n]); both sides coalesced.
__global__ void build_wt_t(const float* __restrict__ W, unsigned short* __restrict__ Wt,
                           int K, int N) {
  __shared__ float tl[32][33];
  int n0 = blockIdx.x * 32, k0 = blockIdx.y * 32;
  int tx = threadIdx.x & 31, ty = threadIdx.x >> 5;   // 256 thr: ty 0..7
#pragma unroll
  for (int i = 0; i < 32; i += 8)
    tl[ty + i][tx] = W[(long)(k0 + ty + i) * N + n0 + tx];
  __syncthreads();
#pragma unroll
  for (int i = 0; i < 32; i += 8)
    Wt[(long)(n0 + ty + i) * K + k0 + tx] = f2b(tl[tx][ty + i]);
}

// Aft[(e*16+r)*P + p] = bf16(A[e][p][r]); LDS-tiled, coalesced.
__global__ void build_aft_t(const float* __restrict__ A, unsigned short* __restrict__ Aft, int P) {
  __shared__ float tl[64][17];
  int e = blockIdx.y; long p0 = (long)blockIdx.x * 64;
  int t = threadIdx.x;
#pragma unroll
  for (int pass = 0; pass < 4; pass++) {
    int idx = t + pass * 256;           // 0..1023
    int pl = idx >> 4, r = idx & 15;
    tl[pl][r] = A[((long)e * P + p0 + pl) * 16 + r];
  }
  __syncthreads();
#pragma unroll
  for (int pass = 0; pass < 4; pass++) {
    int idx = t + pass * 256;
    int r = idx >> 6, pl = idx & 63;
    Aft[(long)(e * 16 + r) * P + p0 + pl] = f2b(tl[pl][r]);
  }
}

// Bft[n*KAUG + kk]: kk<128 -> B_flat[kk*H+n]; kk in [128,136) -> lb[kk-128][n]; else 0.
__global__ void build_bft_t(const float* __restrict__ Bm, const float* __restrict__ lb,
                            unsigned short* __restrict__ Bft, int H) {
  __shared__ float tl[32][33];
  int n0 = blockIdx.x * 32, kk0 = blockIdx.y * 32;
  int tx = threadIdx.x & 31, ty = threadIdx.x >> 5;
#pragma unroll
  for (int i = 0; i < 32; i += 8) {
    int kk = kk0 + ty + i;
    float v;
    if (kk < 128)       v = Bm[(long)kk * H + n0 + tx];
    else if (kk < 136)  v = lb[(long)(kk - 128) * H + n0 + tx];
    else                v = 0.f;
    tl[ty + i][tx] = v;
  }
  __syncthreads();
#pragma unroll
  for (int i = 0; i < 32; i += 8)
    Bft[(long)(n0 + ty + i) * KAUG + kk0 + tx] = f2b(tl[tx][ty + i]);
}

// tg[b][128+j]: j<8 -> gate[b][j]; j in [8,64) -> 0
__global__ void aug_fill(const float* __restrict__ gate, unsigned short* __restrict__ tg) {
  int i = blockIdx.x * blockDim.x + threadIdx.x;  // M*64 threads
  int j = i & 63; int b = i >> 6;
  float v = (j < 8) ? gate[b*8 + j] : 0.f;
  tg[(long)b * KAUG + 128 + j] = f2b(v);
}

// ---------------- 2-phase 64-row GEMM (x@A only) ----------------
template<int MREP>
__global__ __launch_bounds__(256)
void gemm2ph(const unsigned short* __restrict__ A1, int lda1, int K1,
             const unsigned short* __restrict__ Bt1,
             const float* __restrict__ gate,
             void* __restrict__ outp, int ldout) {
  constexpr int BM = MREP * 32;
  __shared__ __attribute__((aligned(16))) unsigned short As[2][BM * 32];
  __shared__ __attribute__((aligned(16))) unsigned short Bs[2][128 * 32];
  const int t = threadIdx.x;
  const int lane = t & 63, wave = t >> 6;
  const int wr = wave >> 1, wc = wave & 1;
  const int row0 = blockIdx.x * BM, col0 = blockIdx.y * 128;
  const int rl = lane & 15, kg = lane >> 4;
  const int kswz = kg ^ ((rl >> 1) & 3);
  const int sr0 = t >> 2;
  const int sc0 = (((t & 3) ^ ((sr0 >> 1) & 3))) * 8;

  f32x4 acc[MREP][4];
#pragma unroll
  for (int m = 0; m < MREP; m++)
#pragma unroll
    for (int n = 0; n < 4; n++) acc[m][n] = (f32x4){0.f, 0.f, 0.f, 0.f};

  auto stage = [&](int buf, int kt) {
    unsigned short* ab = &As[buf][0];
    unsigned short* bb = &Bs[buf][0];
    lds_load16(A1 + (long)(row0 + sr0) * lda1 + kt + sc0, ab + t * 8);
    if constexpr (MREP == 4)
      lds_load16(A1 + (long)(row0 + sr0 + 64) * lda1 + kt + sc0, ab + t * 8 + 2048);
    lds_load16(Bt1 + (long)(col0 + sr0) * K1 + kt + sc0, bb + t * 8);
    lds_load16(Bt1 + (long)(col0 + sr0 + 64) * K1 + kt + sc0, bb + t * 8 + 2048);
  };

  stage(0, 0);
  __syncthreads();
  int cur = 0;
  for (int kt = 0; kt < K1; kt += 32) {
    if (kt + 32 < K1) stage(cur ^ 1, kt + 32);
    bf16x8 af[MREP], bfv[4];
#pragma unroll
    for (int m = 0; m < MREP; m++)
      af[m] = *(const bf16x8*)&As[cur][(wr * (MREP * 16) + m * 16 + rl) * 32 + kswz * 8];
#pragma unroll
    for (int n = 0; n < 4; n++)
      bfv[n] = *(const bf16x8*)&Bs[cur][(wc * 64 + n * 16 + rl) * 32 + kswz * 8];
    __builtin_amdgcn_s_setprio(1);
#pragma unroll
    for (int m = 0; m < MREP; m++)
#pragma unroll
      for (int n = 0; n < 4; n++)
        acc[m][n] = __builtin_amdgcn_mfma_f32_16x16x32_bf16(af[m], bfv[n], acc[m][n], 0, 0, 0);
    __builtin_amdgcn_s_setprio(0);
    __syncthreads();
    cur ^= 1;
  }

#pragma unroll
  for (int m = 0; m < MREP; m++)
#pragma unroll
    for (int n = 0; n < 4; n++)
#pragma unroll
      for (int j = 0; j < 4; j++) {
        int row = row0 + wr * (MREP * 16) + m * 16 + kg * 4 + j;
        int col = col0 + wc * 64 + n * 16 + rl;
        float v = acc[m][n][j] * gate[row * 8 + (col >> 4)];
        ((unsigned short*)outp)[(long)row * ldout + col] = f2b(v);
      }
}

// ---------------- fine-phase main GEMM (m201-style) ----------------
// BM x 128 tile, BK=64, 512 threads = 8 waves (2M x 4N), per-wave BM/2 x 32.
// 3 LDS buffers; tile t+2 staged during tile t -> 2-tile-deep prefetch.
// 2 phases per K-tile, each: {ds_read half of A-frags (+B at ph0) || 1 stage op
//   -> s_barrier -> lgkmcnt(0)+sched_barrier -> setprio(1) MFMA setprio(0) -> s_barrier}.
// Counted vmcnt(L) once per tile at ph1 (L = next tile's loads in flight); never 0 in-loop.
// Swizzle: 16B chunk c of row r holds global chunk c^(r&7); pre-swizzled global
// source (linear global_load_lds dest) + same XOR on ds_read -> 2-way banks (free).
template<int MODE, int BM>
__global__ __launch_bounds__(512)
void gemm_mn(const unsigned short* __restrict__ A1, int lda1, int K1,
             const unsigned short* __restrict__ A2, int lda2, int K2,
             const unsigned short* __restrict__ Bt1, int ldb1,
             const unsigned short* __restrict__ Bt2, int ldb2,
             const float* __restrict__ bias,
             void* __restrict__ outp, int ldout) {
  constexpr int MFRAG = BM / 32;          // per-wave m-fragments (8 or 4)
  constexpr int ATOT = BM * 64;           // ushorts per A buffer
  constexpr int BTOT = 128 * 64;
  constexpr int LA = BM / 64;             // A loads per thread per tile (4 or 2)
  constexpr int L = LA + 2;               // total loads per thread per tile
  __shared__ __attribute__((aligned(16))) unsigned short lds[3 * ATOT + 3 * BTOT];

  const int t = threadIdx.x;
  const int lane = t & 63, wave = t >> 6;
  const int wr = wave >> 2, wc = wave & 3;
  const int rl = lane & 15, kg = lane >> 4;
  const int row0 = blockIdx.x * BM, col0 = blockIdx.y * 128;

  // staging map: chunk ch -> row ch>>3, chunk-col ch&7; content = global chunk (c^(r&7))
  const int sr = t >> 3;                          // base row for ch = t
  const int sk = ((t & 7) ^ (sr & 7)) * 8;        // pre-swizzled source k offset (elems)

  f32x4 acc[MFRAG][2];
#pragma unroll
  for (int m = 0; m < MFRAG; m++)
#pragma unroll
    for (int n = 0; n < 2; n++) acc[m][n] = (f32x4){0.f, 0.f, 0.f, 0.f};

  auto stageA = [&](int buf, int kt) {
    const unsigned short* src; long ld; int kl;
    if (kt < K1) { src = A1; ld = lda1; kl = kt; }
    else         { src = A2; ld = lda2; kl = kt - K1; }
    unsigned short* d = &lds[buf * ATOT + t * 8];
    const unsigned short* s = src + (long)(row0 + sr) * ld + kl + sk;
#pragma unroll
    for (int i = 0; i < LA; i++)
      lds_load16(s + (long)(i * 64) * ld, d + i * 4096);
  };
  auto stageB = [&](int buf, int kt) {
    const unsigned short* src; long ld; int kl;
    if (kt < K1) { src = Bt1; ld = ldb1; kl = kt; }
    else         { src = Bt2; ld = ldb2; kl = kt - K1; }
    unsigned short* d = &lds[3 * ATOT + buf * BTOT + t * 8];
    const unsigned short* s = src + (long)(col0 + sr) * ld + kl + sk;
    lds_load16(s, d);
    lds_load16(s + 64 * ld, d + 4096);
  };
  auto ldA = [&](int buf, int mg, int ks) {     // mg = global m-frag index 0..MFRAG-1
    int lr = wr * (BM / 2) + mg * 16 + rl;
    int sc = (ks * 4 + kg) ^ (lr & 7);
    return *(const bf16x8*)&lds[buf * ATOT + lr * 64 + sc * 8];
  };
  auto ldB = [&](int buf, int n, int ks) {
    int cr = wc * 32 + n * 16 + rl;
    int sc = (ks * 4 + kg) ^ (cr & 7);
    return *(const bf16x8*)&lds[3 * ATOT + buf * BTOT + cr * 64 + sc * 8];
  };

  const int Ktot = K1 + K2;
  const int NT = Ktot / 64;

  // prologue: stage tiles 0 and 1
  stageA(0, 0); stageB(0, 0);
  stageA(1, 64); stageB(1, 64);
  if constexpr (L == 6) asm volatile("s_waitcnt vmcnt(6)" ::: "memory");
  else                  asm volatile("s_waitcnt vmcnt(4)" ::: "memory");
  __builtin_amdgcn_s_barrier();                   // tile 0 resident

  int bcur = 0;
  bf16x8 Bf[2][2];
  for (int tt = 0; tt < NT; ++tt) {
    int bpf = bcur + 2; if (bpf > 2) bpf -= 3;
    const bool pf = (tt + 2 < NT);
    // ---- phase 0: m-frags 0..MFRAG/2-1 ----
    bf16x8 Af[MFRAG / 2][2];
#pragma unroll
    for (int m = 0; m < MFRAG / 2; m++) { Af[m][0] = ldA(bcur, m, 0); Af[m][1] = ldA(bcur, m, 1); }
#pragma unroll
    for (int n = 0; n < 2; n++) { Bf[n][0] = ldB(bcur, n, 0); Bf[n][1] = ldB(bcur, n, 1); }
    if (pf) stageA(bpf, (tt + 2) * 64);
    __builtin_amdgcn_s_barrier();
    asm volatile("s_waitcnt lgkmcnt(0)" ::: "memory");
    __builtin_amdgcn_sched_barrier(0);
    __builtin_amdgcn_s_setprio(1);
#pragma unroll
    for (int m = 0; m < MFRAG / 2; m++)
#pragma unroll
      for (int n = 0; n < 2; n++) {
        acc[m][n] = __builtin_amdgcn_mfma_f32_16x16x32_bf16(Af[m][0], Bf[n][0], acc[m][n], 0, 0, 0);
        acc[m][n] = __builtin_amdgcn_mfma_f32_16x16x32_bf16(Af[m][1], Bf[n][1], acc[m][n], 0, 0, 0);
      }
    __builtin_amdgcn_s_setprio(0);
    __builtin_amdgcn_s_barrier();
    // ---- phase 1: m-frags MFRAG/2..MFRAG-1 ----
#pragma unroll
    for (int m = 0; m < MFRAG / 2; m++) { Af[m][0] = ldA(bcur, MFRAG / 2 + m, 0); Af[m][1] = ldA(bcur, MFRAG / 2 + m, 1); }
    if (pf) stageB(bpf, (tt + 2) * 64);
    if (tt + 1 < NT) {   // drain tile tt+1 (issued 2 tiles ago); keep tile tt+2's L in flight
      if constexpr (L == 6) asm volatile("s_waitcnt vmcnt(6)" ::: "memory");
      else                  asm volatile("s_waitcnt vmcnt(4)" ::: "memory");
    } else {
      asm volatile("s_waitcnt vmcnt(0)" ::: "memory");
    }
    __builtin_amdgcn_s_barrier();
    asm volatile("s_waitcnt lgkmcnt(0)" ::: "memory");
    __builtin_amdgcn_sched_barrier(0);
    __builtin_amdgcn_s_setprio(1);
#pragma unroll
    for (int m = 0; m < MFRAG / 2; m++)
#pragma unroll
      for (int n = 0; n < 2; n++) {
        acc[MFRAG / 2 + m][n] = __builtin_amdgcn_mfma_f32_16x16x32_bf16(Af[m][0], Bf[n][0], acc[MFRAG / 2 + m][n], 0, 0, 0);
        acc[MFRAG / 2 + m][n] = __builtin_amdgcn_mfma_f32_16x16x32_bf16(Af[m][1], Bf[n][1], acc[MFRAG / 2 + m][n], 0, 0, 0);
      }
    __builtin_amdgcn_s_setprio(0);
    __builtin_amdgcn_s_barrier();
    bcur = bcur == 2 ? 0 : bcur + 1;
  }

  // epilogue
#pragma unroll
  for (int m = 0; m < MFRAG; m++)
#pragma unroll
    for (int n = 0; n < 2; n++)
#pragma unroll
      for (int j = 0; j < 4; j++) {
        int row = row0 + wr * (BM / 2) + m * 16 + kg * 4 + j;
        int col = col0 + wc * 32 + n * 16 + rl;
        float v = acc[m][n][j] + bias[col];
        v = fmaxf(v, 0.f);
        if (MODE == 1) ((unsigned short*)outp)[(long)row * ldout + col] = f2b(v);
        else           ((float*)outp)[(long)row * ldout + col] = v;
      }
}

// ---------------- launch ----------------

extern "C" void kernel_launch(void* const* d_in, const int* in_sizes, int n_in,
                              void* d_out, int out_size, void* d_ws, size_t ws_size,
                              hipStream_t stream) {
  (void)in_sizes; (void)n_in; (void)out_size; (void)ws_size;
  const float* dnn = (const float*)d_in[0];
  const int*   dom = (const int*)d_in[1];
  const float* emb = (const float*)d_in[2];
  const float* gW  = (const float*)d_in[3];
  const float* gb  = (const float*)d_in[4];
  const float* Wm[3]  = {(const float*)d_in[5],  (const float*)d_in[10], (const float*)d_in[15]};
  const float* bm[3]  = {(const float*)d_in[6],  (const float*)d_in[11], (const float*)d_in[16]};
  const float* Am[3]  = {(const float*)d_in[7],  (const float*)d_in[12], (const float*)d_in[17]};
  const float* Bm[3]  = {(const float*)d_in[8],  (const float*)d_in[13], (const float*)d_in[18]};
  const float* lbm[3] = {(const float*)d_in[9],  (const float*)d_in[14], (const float*)d_in[19]};

  const int M = M_ROWS;
  const int dIn[3]  = {1024, 1024, 512};
  const int dOutN[3] = {1024, 512, 256};

  char* p = (char*)d_ws;
  auto carve = [&](size_t bytes) { char* r = p; p += (bytes + 255) & ~(size_t)255; return r; };
  float* gate = (float*)carve((size_t)M * 8 * sizeof(float));
  unsigned short* xb0 = (unsigned short*)carve((size_t)M * 1024 * 2);
  unsigned short* xb1 = (unsigned short*)carve((size_t)M * 1024 * 2);
  unsigned short* tg  = (unsigned short*)carve((size_t)M * KAUG * 2);
  unsigned short *Wt[3], *Aft[3], *Bft[3];
  for (int l = 0; l < 3; l++) {
    Wt[l]  = (unsigned short*)carve((size_t)dOutN[l] * dIn[l] * 2);
    Aft[l] = (unsigned short*)carve((size_t)128 * dIn[l] * 2);
    Bft[l] = (unsigned short*)carve((size_t)dOutN[l] * KAUG * 2);
  }

  gate_kernel<<<M / 256, 256, 0, stream>>>(dom, emb, gW, gb, gate);
  {
    int n4 = M * 1024 / 4;
    f32_to_bf16_vec<<<(n4 + 255) / 256, 256, 0, stream>>>(dnn, xb0, n4);
  }
  for (int l = 0; l < 3; l++) {
    build_wt_t<<<dim3(dOutN[l] / 32, dIn[l] / 32), 256, 0, stream>>>(Wm[l], Wt[l], dIn[l], dOutN[l]);
    build_aft_t<<<dim3(dIn[l] / 64, 8), 256, 0, stream>>>(Am[l], Aft[l], dIn[l]);
    build_bft_t<<<dim3(dOutN[l] / 32, KAUG / 32), 256, 0, stream>>>(Bm[l], lbm[l], Bft[l], dOutN[l]);
  }
  aug_fill<<<(M * 64) / 256, 256, 0, stream>>>(gate, tg);

  const unsigned short* xin = xb0;
  for (int l = 0; l < 3; l++) {
    int K1 = dIn[l], N = dOutN[l];
    // tg[:, :128] = gate-scaled x @ A_flat   (64-row tiles -> 256 blocks)
    gemm2ph<2><<<dim3(M / 64, 1), 256, 0, stream>>>(
        xin, K1, K1, Aft[l], gate, (void*)tg, KAUG);
    // out = relu(x @ W + tg_aug @ B_aug + bias)  -- fine-phase deep-pipelined kernel
    if (l == 0)
      gemm_mn<1, 256><<<dim3(M / 256, N / 128), 512, 0, stream>>>(
          xin, K1, K1, tg, KAUG, KAUG, Wt[l], K1, Bft[l], KAUG, bm[l], (void*)xb1, N);
    else if (l == 1)
      gemm_mn<1, 256><<<dim3(M / 256, N / 128), 512, 0, stream>>>(
          xin, K1, K1, tg, KAUG, KAUG, Wt[l], K1, Bft[l], KAUG, bm[l], (void*)xb0, N);
    else
      gemm_mn<2, 128><<<dim3(M / 128, N / 128), 512, 0, stream>>>(
          xin, K1, K1, tg, KAUG, KAUG, Wt[l], K1, Bft[l], KAUG, bm[l], d_out, N);
    xin = (l == 0) ? xb1 : xb0;
  }
}